// Round 1
// baseline (161.568 us; speedup 1.0000x reference)
//
#include <hip/hip_runtime.h>
#include <stdint.h>
#include <math.h>

#define B_DIM 4096
#define H_DIM 1024
#define NI_DIM 4096
#define NQ_DIM 2048
#define K_DIM 5120  // H + NI

typedef __attribute__((ext_vector_type(8))) short short8;
typedef __attribute__((ext_vector_type(4))) float f32x4;

__device__ __forceinline__ unsigned short f2bf(float f) {
  unsigned u = __float_as_uint(f);
  u += 0x7FFFu + ((u >> 16) & 1u);  // round-to-nearest-even
  return (unsigned short)(u >> 16);
}

__device__ __forceinline__ void gload_lds16(const void* g, void* l) {
  __builtin_amdgcn_global_load_lds(
      (__attribute__((address_space(1))) void*)(uintptr_t)g,
      (__attribute__((address_space(3))) void*)l, 16, 0, 0);
}

// fp32 -> bf16 cast, packing a (rows x 2^log2Cols) fp32 matrix into a
// bf16 matrix with row pitch K_DIM at column offset dstColOff.
__global__ __launch_bounds__(256) void cast_pack(
    const float* __restrict__ src, short* __restrict__ dst,
    int log2Cols, int dstColOff, long long total) {
  long long e = ((long long)blockIdx.x * 256 + threadIdx.x) * 8;
  if (e >= total) return;
  long long row = e >> log2Cols;
  int col = (int)(e & ((1LL << log2Cols) - 1));
  float4 v0 = *(const float4*)(src + e);
  float4 v1 = *(const float4*)(src + e + 4);
  short8 o;
  o[0] = (short)f2bf(v0.x); o[1] = (short)f2bf(v0.y);
  o[2] = (short)f2bf(v0.z); o[3] = (short)f2bf(v0.w);
  o[4] = (short)f2bf(v1.x); o[5] = (short)f2bf(v1.y);
  o[6] = (short)f2bf(v1.z); o[7] = (short)f2bf(v1.w);
  *(short8*)(dst + row * (long long)K_DIM + dstColOff + col) = o;
}

// C(4096x1024) = Xc(4096x5120,bf16) . Wc(1024x5120,bf16)^T, then
// hidden = tanh(C + b_t + b_x). 128x128 tile, BK=32, 4 waves (2x2),
// double-buffered LDS with global_load_lds width=16.
__global__ __launch_bounds__(256, 1) void gemm_tanh(
    const short* __restrict__ Xc, const short* __restrict__ Wc,
    const float* __restrict__ bt, const float* __restrict__ bx,
    float* __restrict__ Hout) {
  __shared__ __align__(16) short As[2][128 * 32];
  __shared__ __align__(16) short Bs[2][128 * 32];
  const int tid = threadIdx.x;
  const int lane = tid & 63;
  const int wid = tid >> 6;
  const int wm = wid >> 1, wn = wid & 1;
  const int fr = lane & 15, fq = lane >> 4;
  const int bm = blockIdx.y, bn = blockIdx.x;

  // staging: chunk c (16B = 8 bf16) covers row c/4, k = (c%4)*8 of the tile
  const int c0 = tid, c1 = tid + 256;
  const short* gA0 = Xc + (long long)(bm * 128 + (c0 >> 2)) * K_DIM + ((c0 & 3) << 3);
  const short* gA1 = Xc + (long long)(bm * 128 + (c1 >> 2)) * K_DIM + ((c1 & 3) << 3);
  const short* gB0 = Wc + (long long)(bn * 128 + (c0 >> 2)) * K_DIM + ((c0 & 3) << 3);
  const short* gB1 = Wc + (long long)(bn * 128 + (c1 >> 2)) * K_DIM + ((c1 & 3) << 3);

  f32x4 acc[4][4] = {};

  // prologue: stage K-tile 0 into buffer 0
  gload_lds16(gA0, &As[0][c0 * 8]);
  gload_lds16(gA1, &As[0][c1 * 8]);
  gload_lds16(gB0, &Bs[0][c0 * 8]);
  gload_lds16(gB1, &Bs[0][c1 * 8]);
  __syncthreads();  // compiler drains vmcnt(0) before s_barrier

  int cur = 0;
  for (int kt = 0; kt < K_DIM; kt += 32) {
    int nxt = kt + 32;
    if (nxt < K_DIM) {  // prefetch next K-tile into the other buffer
      gload_lds16(gA0 + nxt, &As[cur ^ 1][c0 * 8]);
      gload_lds16(gA1 + nxt, &As[cur ^ 1][c1 * 8]);
      gload_lds16(gB0 + nxt, &Bs[cur ^ 1][c0 * 8]);
      gload_lds16(gB1 + nxt, &Bs[cur ^ 1][c1 * 8]);
    }
    const short* a_base = &As[cur][0];
    const short* b_base = &Bs[cur][0];
    short8 av[4], bv[4];
#pragma unroll
    for (int i = 0; i < 4; i++) {
      av[i] = *(const short8*)(a_base + (wm * 64 + i * 16 + fr) * 32 + fq * 8);
      bv[i] = *(const short8*)(b_base + (wn * 64 + i * 16 + fr) * 32 + fq * 8);
    }
#pragma unroll
    for (int mi = 0; mi < 4; mi++)
#pragma unroll
      for (int ni = 0; ni < 4; ni++)
        acc[mi][ni] = __builtin_amdgcn_mfma_f32_16x16x32_bf16(
            av[mi], bv[ni], acc[mi][ni], 0, 0, 0);
    __syncthreads();  // drains prefetch vmcnt + protects buffer reuse
    cur ^= 1;
  }

  // epilogue: C/D layout col=lane&15, row=(lane>>4)*4+reg
  const int row0 = bm * 128 + wm * 64;
  const int col0 = bn * 128 + wn * 64;
#pragma unroll
  for (int ni = 0; ni < 4; ni++) {
    int col = col0 + ni * 16 + fr;
    float bias = bt[col] + bx[col];
#pragma unroll
    for (int mi = 0; mi < 4; mi++) {
#pragma unroll
      for (int r = 0; r < 4; r++) {
        int row = row0 + mi * 16 + fq * 4 + r;
        Hout[(long long)row * H_DIM + col] = tanhf(acc[mi][ni][r] + bias);
      }
    }
  }
}

// One block per batch row: find one-hot index(es) in inputY, dot hidden row
// with the selected W_y row(s), sigmoid, write pred + per-row BCE term.
__global__ __launch_bounds__(256) void pred_err(
    const float* __restrict__ hidden, const float* __restrict__ Y,
    const float* __restrict__ truth, const float* __restrict__ Wy,
    const float* __restrict__ by, float* __restrict__ predOut,
    float* __restrict__ bce) {
  const int b = blockIdx.x;
  const int tid = threadIdx.x;
  __shared__ int s_cnt;
  __shared__ int s_idx[8];
  __shared__ float s_val[8];
  __shared__ float s_red[4];
  if (tid == 0) s_cnt = 0;
  __syncthreads();
  const float* Yr = Y + (long long)b * NQ_DIM;
  for (int j = tid; j < NQ_DIM; j += 256) {
    float v = Yr[j];
    if (v != 0.0f) {
      int p = atomicAdd(&s_cnt, 1);
      if (p < 8) { s_idx[p] = j; s_val[p] = v; }
    }
  }
  __syncthreads();
  int cnt = s_cnt < 8 ? s_cnt : 8;
  const float* Hr = hidden + (long long)b * H_DIM;
  // hidden starts at d_out+4097 floats -> not 16B aligned; scalar loads
  float h0 = Hr[tid * 4 + 0], h1 = Hr[tid * 4 + 1];
  float h2 = Hr[tid * 4 + 2], h3 = Hr[tid * 4 + 3];
  float predv = 0.0f;
  for (int it = 0; it < cnt; ++it) {
    int q = s_idx[it];
    float4 w = *(const float4*)(Wy + (long long)q * H_DIM + tid * 4);
    float part = h0 * w.x + h1 * w.y + h2 * w.z + h3 * w.w;
#pragma unroll
    for (int off = 32; off > 0; off >>= 1) part += __shfl_down(part, off, 64);
    if ((tid & 63) == 0) s_red[tid >> 6] = part;
    __syncthreads();
    if (tid == 0) {
      float z = s_red[0] + s_red[1] + s_red[2] + s_red[3] + by[q];
      float p = 1.0f / (1.0f + expf(-z));
      predv += s_val[it] * p;
    }
    __syncthreads();
  }
  if (tid == 0) {
    predOut[b] = predv;
    float t = truth[b];
    float lp = fmaxf(logf(predv), -100.0f);
    float l1p = fmaxf(log1pf(-predv), -100.0f);
    bce[b] = -(t * lp + (1.0f - t) * l1p);
  }
}

__global__ __launch_bounds__(256) void reduce_err(
    const float* __restrict__ bce, float* __restrict__ errOut) {
  float s = 0.0f;
  for (int i = threadIdx.x; i < B_DIM; i += 256) s += bce[i];
#pragma unroll
  for (int off = 32; off > 0; off >>= 1) s += __shfl_down(s, off, 64);
  __shared__ float red[4];
  if ((threadIdx.x & 63) == 0) red[threadIdx.x >> 6] = s;
  __syncthreads();
  if (threadIdx.x == 0) errOut[0] = red[0] + red[1] + red[2] + red[3];
}

extern "C" void kernel_launch(void* const* d_in, const int* in_sizes, int n_in,
                              void* d_out, int out_size, void* d_ws, size_t ws_size,
                              hipStream_t stream) {
  (void)in_sizes; (void)n_in; (void)out_size; (void)ws_size;
  const float* state  = (const float*)d_in[0];
  const float* inputX = (const float*)d_in[1];
  const float* inputY = (const float*)d_in[2];
  const float* truth  = (const float*)d_in[3];
  const float* W_t    = (const float*)d_in[4];
  const float* b_t    = (const float*)d_in[5];
  const float* W_x    = (const float*)d_in[6];
  const float* b_x    = (const float*)d_in[7];
  const float* W_y    = (const float*)d_in[8];
  const float* b_y    = (const float*)d_in[9];

  // workspace: Xcat bf16 (4096x5120) | Wcat bf16 (1024x5120) | bce f32 (4096)
  short* Xc = (short*)d_ws;
  short* Wc = (short*)((char*)d_ws + (size_t)B_DIM * K_DIM * 2);
  float* bce = (float*)((char*)d_ws + (size_t)B_DIM * K_DIM * 2 + (size_t)H_DIM * K_DIM * 2);

  float* predOut = (float*)d_out;             // [0 .. 4095]
  float* errOut  = predOut + B_DIM;           // [4096]
  float* hidden  = predOut + B_DIM + 1;       // [4097 ..]

  cast_pack<<<(B_DIM * H_DIM / 2048), 256, 0, stream>>>(
      state, Xc, 10, 0, (long long)B_DIM * H_DIM);
  cast_pack<<<(B_DIM * NI_DIM / 2048), 256, 0, stream>>>(
      inputX, Xc, 12, H_DIM, (long long)B_DIM * NI_DIM);
  cast_pack<<<(H_DIM * H_DIM / 2048), 256, 0, stream>>>(
      W_t, Wc, 10, 0, (long long)H_DIM * H_DIM);
  cast_pack<<<(H_DIM * NI_DIM / 2048), 256, 0, stream>>>(
      W_x, Wc, 12, H_DIM, (long long)H_DIM * NI_DIM);
  gemm_tanh<<<dim3(H_DIM / 128, B_DIM / 128), 256, 0, stream>>>(
      Xc, Wc, b_t, b_x, hidden);
  pred_err<<<B_DIM, 256, 0, stream>>>(hidden, inputY, truth, W_y, b_y, predOut, bce);
  reduce_err<<<1, 256, 0, stream>>>(bce, errOut);
}

// Round 2
// 134.864 us; speedup vs baseline: 1.1980x; 1.1980x over previous
//
#include <hip/hip_runtime.h>
#include <stdint.h>
#include <math.h>

#define B_DIM 4096
#define H_DIM 1024
#define NI_DIM 4096
#define NQ_DIM 2048
#define K_DIM 5120  // H + NI

typedef __attribute__((ext_vector_type(8))) short short8;
typedef __attribute__((ext_vector_type(4))) float f32x4;

__device__ __forceinline__ unsigned short f2bf(float f) {
  unsigned u = __float_as_uint(f);
  u += 0x7FFFu + ((u >> 16) & 1u);  // round-to-nearest-even
  return (unsigned short)(u >> 16);
}

__device__ __forceinline__ void gload_lds16(const void* g, void* l) {
  __builtin_amdgcn_global_load_lds(
      (__attribute__((address_space(1))) void*)(uintptr_t)g,
      (__attribute__((address_space(3))) void*)l, 16, 0, 0);
}

// fp32 -> bf16 cast, packing a (rows x 2^log2Cols) fp32 matrix into a
// bf16 matrix with row pitch K_DIM at column offset dstColOff.
__global__ __launch_bounds__(256) void cast_pack(
    const float* __restrict__ src, short* __restrict__ dst,
    int log2Cols, int dstColOff, long long total) {
  long long e = ((long long)blockIdx.x * 256 + threadIdx.x) * 8;
  if (e >= total) return;
  long long row = e >> log2Cols;
  int col = (int)(e & ((1LL << log2Cols) - 1));
  float4 v0 = *(const float4*)(src + e);
  float4 v1 = *(const float4*)(src + e + 4);
  short8 o;
  o[0] = (short)f2bf(v0.x); o[1] = (short)f2bf(v0.y);
  o[2] = (short)f2bf(v0.z); o[3] = (short)f2bf(v0.w);
  o[4] = (short)f2bf(v1.x); o[5] = (short)f2bf(v1.y);
  o[6] = (short)f2bf(v1.z); o[7] = (short)f2bf(v1.w);
  *(short8*)(dst + row * (long long)K_DIM + dstColOff + col) = o;
}

// Split-K GEMM: P[z](4096x1024,f32) = Xc . Wc^T over K-range z.
// 128x128 tile, BK=32, 4 waves (2x2), dbuf LDS via global_load_lds w=16.
// LDS XOR-swizzle: 16B slot p at row r holds logical k-slot (p ^ (r&3)).
// Staging keeps LDS linear (gload_lds constraint) and pre-swizzles the
// GLOBAL source k-offset; ds_read applies the same XOR (rule: both sides).
__global__ __launch_bounds__(256, 4) void gemm_splitk(
    const short* __restrict__ Xc, const short* __restrict__ Wc,
    float* __restrict__ P, int Ksplit) {
  __shared__ __align__(16) short As[2][128 * 32];
  __shared__ __align__(16) short Bs[2][128 * 32];
  const int tid = threadIdx.x;
  const int lane = tid & 63;
  const int wid = tid >> 6;
  const int wm = wid >> 1, wn = wid & 1;
  const int fr = lane & 15, fq = lane >> 4;
  const int bm = blockIdx.y, bn = blockIdx.x, bz = blockIdx.z;
  const int k0 = bz * Ksplit;

  // staging chunk c (16B): LDS row c>>2, physical slot c&3,
  // global logical slot = (c&3) ^ ((c>>2)&3)
  const int c0 = tid, c1 = tid + 256;
  const int gk0 = (((c0 & 3) ^ ((c0 >> 2) & 3)) << 3);
  const int gk1 = (((c1 & 3) ^ ((c1 >> 2) & 3)) << 3);
  const short* gA0 = Xc + (long long)(bm * 128 + (c0 >> 2)) * K_DIM + k0 + gk0;
  const short* gA1 = Xc + (long long)(bm * 128 + (c1 >> 2)) * K_DIM + k0 + gk1;
  const short* gB0 = Wc + (long long)(bn * 128 + (c0 >> 2)) * K_DIM + k0 + gk0;
  const short* gB1 = Wc + (long long)(bn * 128 + (c1 >> 2)) * K_DIM + k0 + gk1;

  // ds_read physical slot for logical slot fq at row r: fq ^ (r&3), r&3 == fr&3
  const int rdslot = ((fq ^ (fr & 3)) << 3);

  f32x4 acc[4][4] = {};

  gload_lds16(gA0, &As[0][c0 * 16 / 2]);
  gload_lds16(gA1, &As[0][c1 * 16 / 2]);
  gload_lds16(gB0, &Bs[0][c0 * 16 / 2]);
  gload_lds16(gB1, &Bs[0][c1 * 16 / 2]);
  __syncthreads();

  int cur = 0;
  for (int kt = 0; kt < Ksplit; kt += 32) {
    int nxt = kt + 32;
    if (nxt < Ksplit) {
      gload_lds16(gA0 + nxt, &As[cur ^ 1][c0 * 8]);
      gload_lds16(gA1 + nxt, &As[cur ^ 1][c1 * 8]);
      gload_lds16(gB0 + nxt, &Bs[cur ^ 1][c0 * 8]);
      gload_lds16(gB1 + nxt, &Bs[cur ^ 1][c1 * 8]);
    }
    const short* a_base = &As[cur][0];
    const short* b_base = &Bs[cur][0];
    short8 av[4], bv[4];
#pragma unroll
    for (int i = 0; i < 4; i++) {
      av[i] = *(const short8*)(a_base + (wm * 64 + i * 16 + fr) * 32 + rdslot);
      bv[i] = *(const short8*)(b_base + (wn * 64 + i * 16 + fr) * 32 + rdslot);
    }
#pragma unroll
    for (int mi = 0; mi < 4; mi++)
#pragma unroll
      for (int ni = 0; ni < 4; ni++)
        acc[mi][ni] = __builtin_amdgcn_mfma_f32_16x16x32_bf16(
            av[mi], bv[ni], acc[mi][ni], 0, 0, 0);
    __syncthreads();
    cur ^= 1;
  }

  // write fp32 partial; C/D layout col=lane&15, row=(lane>>4)*4+reg
  float* Pp = P + (long long)bz * B_DIM * H_DIM;
  const int row0 = bm * 128 + wm * 64;
  const int col0 = bn * 128 + wn * 64;
#pragma unroll
  for (int ni = 0; ni < 4; ni++) {
    int col = col0 + ni * 16 + fr;
#pragma unroll
    for (int mi = 0; mi < 4; mi++) {
#pragma unroll
      for (int r = 0; r < 4; r++) {
        int row = row0 + mi * 16 + fq * 4 + r;
        Pp[(long long)row * H_DIM + col] = acc[mi][ni][r];
      }
    }
  }
}

// hidden = tanh(sum_z P[z] + b_t + b_x); hidden base is NOT 16B-aligned
// (d_out + 4097 floats) -> scalar stores.
__global__ __launch_bounds__(256) void reduce_bias_tanh(
    const float* __restrict__ P, const float* __restrict__ bt,
    const float* __restrict__ bx, float* __restrict__ hidden, int S) {
  const long long total4 = (long long)B_DIM * H_DIM / 4;
  for (long long e = (long long)blockIdx.x * 256 + threadIdx.x; e < total4;
       e += (long long)gridDim.x * 256) {
    long long base = e * 4;
    int col = (int)(base & (H_DIM - 1));
    float4 s = *(const float4*)(P + base);
    for (int z = 1; z < S; ++z) {
      float4 p = *(const float4*)(P + (long long)z * B_DIM * H_DIM + base);
      s.x += p.x; s.y += p.y; s.z += p.z; s.w += p.w;
    }
    float4 bt4 = *(const float4*)(bt + col);
    float4 bx4 = *(const float4*)(bx + col);
    hidden[base + 0] = tanhf(s.x + bt4.x + bx4.x);
    hidden[base + 1] = tanhf(s.y + bt4.y + bx4.y);
    hidden[base + 2] = tanhf(s.z + bt4.z + bx4.z);
    hidden[base + 3] = tanhf(s.w + bt4.w + bx4.w);
  }
}

// One block per batch row: find one-hot index(es) in inputY, dot hidden row
// with the selected W_y row(s), sigmoid, write pred + per-row BCE term.
__global__ __launch_bounds__(256) void pred_err(
    const float* __restrict__ hidden, const float* __restrict__ Y,
    const float* __restrict__ truth, const float* __restrict__ Wy,
    const float* __restrict__ by, float* __restrict__ predOut,
    float* __restrict__ bce) {
  const int b = blockIdx.x;
  const int tid = threadIdx.x;
  __shared__ int s_cnt;
  __shared__ int s_idx[8];
  __shared__ float s_val[8];
  __shared__ float s_red[4];
  if (tid == 0) s_cnt = 0;
  __syncthreads();
  const float* Yr = Y + (long long)b * NQ_DIM;
  for (int j = tid; j < NQ_DIM; j += 256) {
    float v = Yr[j];
    if (v != 0.0f) {
      int p = atomicAdd(&s_cnt, 1);
      if (p < 8) { s_idx[p] = j; s_val[p] = v; }
    }
  }
  __syncthreads();
  int cnt = s_cnt < 8 ? s_cnt : 8;
  const float* Hr = hidden + (long long)b * H_DIM;
  float h0 = Hr[tid * 4 + 0], h1 = Hr[tid * 4 + 1];
  float h2 = Hr[tid * 4 + 2], h3 = Hr[tid * 4 + 3];
  float predv = 0.0f;
  for (int it = 0; it < cnt; ++it) {
    int q = s_idx[it];
    float4 w = *(const float4*)(Wy + (long long)q * H_DIM + tid * 4);
    float part = h0 * w.x + h1 * w.y + h2 * w.z + h3 * w.w;
#pragma unroll
    for (int off = 32; off > 0; off >>= 1) part += __shfl_down(part, off, 64);
    if ((tid & 63) == 0) s_red[tid >> 6] = part;
    __syncthreads();
    if (tid == 0) {
      float z = s_red[0] + s_red[1] + s_red[2] + s_red[3] + by[q];
      float p = 1.0f / (1.0f + expf(-z));
      predv += s_val[it] * p;
    }
    __syncthreads();
  }
  if (tid == 0) {
    predOut[b] = predv;
    float t = truth[b];
    float lp = fmaxf(logf(predv), -100.0f);
    float l1p = fmaxf(log1pf(-predv), -100.0f);
    bce[b] = -(t * lp + (1.0f - t) * l1p);
  }
}

__global__ __launch_bounds__(256) void reduce_err(
    const float* __restrict__ bce, float* __restrict__ errOut) {
  float s = 0.0f;
  for (int i = threadIdx.x; i < B_DIM; i += 256) s += bce[i];
#pragma unroll
  for (int off = 32; off > 0; off >>= 1) s += __shfl_down(s, off, 64);
  __shared__ float red[4];
  if ((threadIdx.x & 63) == 0) red[threadIdx.x >> 6] = s;
  __syncthreads();
  if (threadIdx.x == 0) errOut[0] = red[0] + red[1] + red[2] + red[3];
}

extern "C" void kernel_launch(void* const* d_in, const int* in_sizes, int n_in,
                              void* d_out, int out_size, void* d_ws, size_t ws_size,
                              hipStream_t stream) {
  (void)in_sizes; (void)n_in; (void)out_size;
  const float* state  = (const float*)d_in[0];
  const float* inputX = (const float*)d_in[1];
  const float* inputY = (const float*)d_in[2];
  const float* truth  = (const float*)d_in[3];
  const float* W_t    = (const float*)d_in[4];
  const float* b_t    = (const float*)d_in[5];
  const float* W_x    = (const float*)d_in[6];
  const float* b_x    = (const float*)d_in[7];
  const float* W_y    = (const float*)d_in[8];
  const float* b_y    = (const float*)d_in[9];

  const size_t XC_B = (size_t)B_DIM * K_DIM * 2;   // 41.9 MB
  const size_t WC_B = (size_t)H_DIM * K_DIM * 2;   // 10.5 MB
  const size_t PART = (size_t)B_DIM * H_DIM * 4;   // 16.8 MB per split

  // pick split count by workspace headroom
  int S = 1;
  if (ws_size >= XC_B + WC_B + 4 * PART + 16384) S = 4;
  else if (ws_size >= XC_B + WC_B + 2 * PART + 16384) S = 2;

  short* Xc = (short*)d_ws;
  short* Wc = (short*)((char*)d_ws + XC_B);
  float* P  = (float*)((char*)d_ws + XC_B + WC_B);
  float* bce = (float*)((char*)d_ws + XC_B + WC_B + (size_t)S * PART);

  float* predOut = (float*)d_out;             // [0 .. 4095]
  float* errOut  = predOut + B_DIM;           // [4096]
  float* hidden  = predOut + B_DIM + 1;       // [4097 ..]

  cast_pack<<<(B_DIM * H_DIM / 2048), 256, 0, stream>>>(
      state, Xc, 10, 0, (long long)B_DIM * H_DIM);
  cast_pack<<<(B_DIM * NI_DIM / 2048), 256, 0, stream>>>(
      inputX, Xc, 12, H_DIM, (long long)B_DIM * NI_DIM);
  cast_pack<<<(H_DIM * H_DIM / 2048), 256, 0, stream>>>(
      W_t, Wc, 10, 0, (long long)H_DIM * H_DIM);
  cast_pack<<<(H_DIM * NI_DIM / 2048), 256, 0, stream>>>(
      W_x, Wc, 12, H_DIM, (long long)H_DIM * NI_DIM);

  gemm_splitk<<<dim3(H_DIM / 128, B_DIM / 128, S), 256, 0, stream>>>(
      Xc, Wc, P, K_DIM / S);
  reduce_bias_tanh<<<2048, 256, 0, stream>>>(P, b_t, b_x, hidden, S);

  pred_err<<<B_DIM, 256, 0, stream>>>(hidden, inputY, truth, W_y, b_y, predOut, bce);
  reduce_err<<<1, 256, 0, stream>>>(bce, errOut);
}

// Round 3
// 108.989 us; speedup vs baseline: 1.4824x; 1.2374x over previous
//
#include <hip/hip_runtime.h>
#include <stdint.h>
#include <math.h>

#define B_DIM 4096
#define H_DIM 1024
#define NI_DIM 4096
#define NQ_DIM 2048
#define K_DIM 5120   // H + NI
#define NKT 160      // K_DIM / 32

typedef __attribute__((ext_vector_type(8))) short short8;
typedef __attribute__((ext_vector_type(4))) float f32x4;

__device__ __forceinline__ unsigned short f2bf(float f) {
  unsigned u = __float_as_uint(f);
  u += 0x7FFFu + ((u >> 16) & 1u);  // round-to-nearest-even
  return (unsigned short)(u >> 16);
}

__device__ __forceinline__ void gload_lds16(const void* g, void* l) {
  __builtin_amdgcn_global_load_lds(
      (__attribute__((address_space(1))) void*)(uintptr_t)g,
      (__attribute__((address_space(3))) void*)l, 16, 0, 0);
}

// fp32 -> bf16 cast into staged-tile layout:
//   dst chunk16 index = ((rowTile*NKT + kt)*4 + slot)*128 + row_in_tile
// so GEMM staging reads are contiguous 16B chunks AND the implied LDS
// layout [slot][row][8] makes ds_read_b128 the canonical (conflict-free)
// granule pattern. One block per (rowTile, kt): reads a 128x32 fp32 tile
// coalesced, bounces through 8KB LDS, writes 8KB bf16 contiguous.
// Columns 0..1023 come from src0 (1024-col matrix), 1024..5119 from src1
// (4096-col matrix) -- true for both [state|inputX] and [W_t|W_x].
__global__ __launch_bounds__(256) void cast_tile(
    const float* __restrict__ src0, const float* __restrict__ src1,
    short* __restrict__ dst) {
  __shared__ __align__(16) short lds[4096];  // [4][128][8]
  const unsigned bt = blockIdx.x;
  const int rowTile = bt / NKT;
  const int kt = bt % NKT;
  const float* src;
  long long srcBase;
  int cols;
  if (kt < 32) { src = src0; cols = 1024; srcBase = (long long)kt * 32; }
  else         { src = src1; cols = 4096; srcBase = (long long)(kt - 32) * 32; }
  const int tid = threadIdx.x;
#pragma unroll
  for (int half = 0; half < 2; ++half) {
    int c = tid + half * 256;          // cell: row r = c>>2, slot s = c&3
    int r = c >> 2, s = c & 3;
    long long sa = ((long long)(rowTile * 128 + r)) * cols + srcBase + s * 8;
    float4 v0 = *(const float4*)(src + sa);
    float4 v1 = *(const float4*)(src + sa + 4);
    short8 o;
    o[0] = (short)f2bf(v0.x); o[1] = (short)f2bf(v0.y);
    o[2] = (short)f2bf(v0.z); o[3] = (short)f2bf(v0.w);
    o[4] = (short)f2bf(v1.x); o[5] = (short)f2bf(v1.y);
    o[6] = (short)f2bf(v1.z); o[7] = (short)f2bf(v1.w);
    *(short8*)(&lds[(s * 128 + r) * 8]) = o;
  }
  __syncthreads();
  short* dtile = dst + (((long long)rowTile * NKT + kt) * 512) * 8;
#pragma unroll
  for (int half = 0; half < 2; ++half) {
    int c = tid + half * 256;
    *(short8*)(dtile + c * 8) = *(const short8*)(&lds[c * 8]);
  }
}

// Split-K GEMM on staged-tile inputs. 128x128 tile, BK=32, 4 waves (2x2),
// double-buffered LDS via global_load_lds w=16 (contiguous both sides).
// XCD-aware bijective swizzle on the flattened grid (nwg % 8 == 0).
__global__ __launch_bounds__(256, 4) void gemm_splitk(
    const short* __restrict__ Xc, const short* __restrict__ Wc,
    float* __restrict__ P, int ntk) {
  __shared__ __align__(16) short As[2][4096];
  __shared__ __align__(16) short Bs[2][4096];
  const int tid = threadIdx.x;
  const int lane = tid & 63;
  const int wid = tid >> 6;
  const int wm = wid >> 1, wn = wid & 1;
  const int fr = lane & 15, fq = lane >> 4;

  const int nwg = gridDim.x;
  const int orig = blockIdx.x;
  const int cpx = nwg >> 3;
  const int swz = (orig & 7) * cpx + (orig >> 3);
  const int bz = swz >> 8;
  const int bm = (swz >> 3) & 31;
  const int bn = swz & 7;
  const int kt0 = bz * ntk;

  const int c0 = tid, c1 = tid + 256;
  const short* gA = Xc + (((long long)bm * NKT + kt0) << 12);  // *4096 shorts
  const short* gB = Wc + (((long long)bn * NKT + kt0) << 12);

  f32x4 acc[4][4] = {};

  gload_lds16(gA + c0 * 8, &As[0][c0 * 8]);
  gload_lds16(gA + c1 * 8, &As[0][c1 * 8]);
  gload_lds16(gB + c0 * 8, &Bs[0][c0 * 8]);
  gload_lds16(gB + c1 * 8, &Bs[0][c1 * 8]);
  __syncthreads();

  int cur = 0;
  for (int t = 0; t < ntk; ++t) {
    if (t + 1 < ntk) {
      const short* nA = gA + (t + 1) * 4096;
      const short* nB = gB + (t + 1) * 4096;
      gload_lds16(nA + c0 * 8, &As[cur ^ 1][c0 * 8]);
      gload_lds16(nA + c1 * 8, &As[cur ^ 1][c1 * 8]);
      gload_lds16(nB + c0 * 8, &Bs[cur ^ 1][c0 * 8]);
      gload_lds16(nB + c1 * 8, &Bs[cur ^ 1][c1 * 8]);
    }
    const short* a_base = &As[cur][0];
    const short* b_base = &Bs[cur][0];
    short8 av[4], bv[4];
#pragma unroll
    for (int i = 0; i < 4; i++) {
      // [slot=fq][row = w*64 + i*16 + fr][8] -> granule = fr&7 (canonical)
      av[i] = *(const short8*)(a_base + (fq * 128 + wm * 64 + i * 16 + fr) * 8);
      bv[i] = *(const short8*)(b_base + (fq * 128 + wn * 64 + i * 16 + fr) * 8);
    }
#pragma unroll
    for (int mi = 0; mi < 4; mi++)
#pragma unroll
      for (int ni = 0; ni < 4; ni++)
        acc[mi][ni] = __builtin_amdgcn_mfma_f32_16x16x32_bf16(
            av[mi], bv[ni], acc[mi][ni], 0, 0, 0);
    __syncthreads();
    cur ^= 1;
  }

  // write fp32 partial; C/D layout col=lane&15, row=(lane>>4)*4+reg
  float* Pp = P + (long long)bz * B_DIM * H_DIM;
  const int row0 = bm * 128 + wm * 64;
  const int col0 = bn * 128 + wn * 64;
#pragma unroll
  for (int ni = 0; ni < 4; ni++) {
    int col = col0 + ni * 16 + fr;
#pragma unroll
    for (int mi = 0; mi < 4; mi++) {
#pragma unroll
      for (int r = 0; r < 4; r++) {
        int row = row0 + mi * 16 + fq * 4 + r;
        Pp[(long long)row * H_DIM + col] = acc[mi][ni][r];
      }
    }
  }
}

// hidden = tanh(sum_z P[z] + b_t + b_x); hidden base is NOT 16B-aligned
// (d_out + 4097 floats) -> scalar stores.
__global__ __launch_bounds__(256) void reduce_bias_tanh(
    const float* __restrict__ P, const float* __restrict__ bt,
    const float* __restrict__ bx, float* __restrict__ hidden, int S) {
  const long long total4 = (long long)B_DIM * H_DIM / 4;
  for (long long e = (long long)blockIdx.x * 256 + threadIdx.x; e < total4;
       e += (long long)gridDim.x * 256) {
    long long base = e * 4;
    int col = (int)(base & (H_DIM - 1));
    float4 s = *(const float4*)(P + base);
    for (int z = 1; z < S; ++z) {
      float4 p = *(const float4*)(P + (long long)z * B_DIM * H_DIM + base);
      s.x += p.x; s.y += p.y; s.z += p.z; s.w += p.w;
    }
    float4 bt4 = *(const float4*)(bt + col);
    float4 bx4 = *(const float4*)(bx + col);
    hidden[base + 0] = tanhf(s.x + bt4.x + bx4.x);
    hidden[base + 1] = tanhf(s.y + bt4.y + bx4.y);
    hidden[base + 2] = tanhf(s.z + bt4.z + bx4.z);
    hidden[base + 3] = tanhf(s.w + bt4.w + bx4.w);
  }
}

// One block per batch row: find one-hot index(es) in inputY (float4 scan),
// dot hidden row with selected W_y row(s), sigmoid, pred + BCE term.
__global__ __launch_bounds__(256) void pred_err(
    const float* __restrict__ hidden, const float* __restrict__ Y,
    const float* __restrict__ truth, const float* __restrict__ Wy,
    const float* __restrict__ by, float* __restrict__ predOut,
    float* __restrict__ bce) {
  const int b = blockIdx.x;
  const int tid = threadIdx.x;
  __shared__ int s_cnt;
  __shared__ int s_idx[8];
  __shared__ float s_val[8];
  __shared__ float s_red[4];
  if (tid == 0) s_cnt = 0;
  __syncthreads();
  const float4* Yr = (const float4*)(Y + (long long)b * NQ_DIM);
#pragma unroll
  for (int h = 0; h < NQ_DIM / 4 / 256; ++h) {
    int j = tid + h * 256;
    float4 v = Yr[j];
    if (v.x != 0.0f) { int p = atomicAdd(&s_cnt, 1); if (p < 8) { s_idx[p] = 4 * j;     s_val[p] = v.x; } }
    if (v.y != 0.0f) { int p = atomicAdd(&s_cnt, 1); if (p < 8) { s_idx[p] = 4 * j + 1; s_val[p] = v.y; } }
    if (v.z != 0.0f) { int p = atomicAdd(&s_cnt, 1); if (p < 8) { s_idx[p] = 4 * j + 2; s_val[p] = v.z; } }
    if (v.w != 0.0f) { int p = atomicAdd(&s_cnt, 1); if (p < 8) { s_idx[p] = 4 * j + 3; s_val[p] = v.w; } }
  }
  __syncthreads();
  int cnt = s_cnt < 8 ? s_cnt : 8;
  const float* Hr = hidden + (long long)b * H_DIM;
  float h0 = Hr[tid * 4 + 0], h1 = Hr[tid * 4 + 1];
  float h2 = Hr[tid * 4 + 2], h3 = Hr[tid * 4 + 3];
  float predv = 0.0f;
  for (int it = 0; it < cnt; ++it) {
    int q = s_idx[it];
    float4 w = *(const float4*)(Wy + (long long)q * H_DIM + tid * 4);
    float part = h0 * w.x + h1 * w.y + h2 * w.z + h3 * w.w;
#pragma unroll
    for (int off = 32; off > 0; off >>= 1) part += __shfl_down(part, off, 64);
    if ((tid & 63) == 0) s_red[tid >> 6] = part;
    __syncthreads();
    if (tid == 0) {
      float z = s_red[0] + s_red[1] + s_red[2] + s_red[3] + by[q];
      float p = 1.0f / (1.0f + expf(-z));
      predv += s_val[it] * p;
    }
    __syncthreads();
  }
  if (tid == 0) {
    predOut[b] = predv;
    float t = truth[b];
    float lp = fmaxf(logf(predv), -100.0f);
    float l1p = fmaxf(log1pf(-predv), -100.0f);
    bce[b] = -(t * lp + (1.0f - t) * l1p);
  }
}

__global__ __launch_bounds__(256) void reduce_err(
    const float* __restrict__ bce, float* __restrict__ errOut) {
  float s = 0.0f;
  for (int i = threadIdx.x; i < B_DIM; i += 256) s += bce[i];
#pragma unroll
  for (int off = 32; off > 0; off >>= 1) s += __shfl_down(s, off, 64);
  __shared__ float red[4];
  if ((threadIdx.x & 63) == 0) red[threadIdx.x >> 6] = s;
  __syncthreads();
  if (threadIdx.x == 0) errOut[0] = red[0] + red[1] + red[2] + red[3];
}

extern "C" void kernel_launch(void* const* d_in, const int* in_sizes, int n_in,
                              void* d_out, int out_size, void* d_ws, size_t ws_size,
                              hipStream_t stream) {
  (void)in_sizes; (void)n_in; (void)out_size;
  const float* state  = (const float*)d_in[0];
  const float* inputX = (const float*)d_in[1];
  const float* inputY = (const float*)d_in[2];
  const float* truth  = (const float*)d_in[3];
  const float* W_t    = (const float*)d_in[4];
  const float* b_t    = (const float*)d_in[5];
  const float* W_x    = (const float*)d_in[6];
  const float* b_x    = (const float*)d_in[7];
  const float* W_y    = (const float*)d_in[8];
  const float* b_y    = (const float*)d_in[9];

  const size_t XC_B = (size_t)B_DIM * K_DIM * 2;   // 41.9 MB
  const size_t WC_B = (size_t)H_DIM * K_DIM * 2;   // 10.5 MB
  const size_t PART = (size_t)B_DIM * H_DIM * 4;   // 16.8 MB per split

  int S = 1;
  if (ws_size >= XC_B + WC_B + 4 * PART + 16384) S = 4;
  else if (ws_size >= XC_B + WC_B + 2 * PART + 16384) S = 2;

  short* Xc = (short*)d_ws;
  short* Wc = (short*)((char*)d_ws + XC_B);
  float* P  = (float*)((char*)d_ws + XC_B + WC_B);
  float* bce = (float*)((char*)d_ws + XC_B + WC_B + (size_t)S * PART);

  float* predOut = (float*)d_out;             // [0 .. 4095]
  float* errOut  = predOut + B_DIM;           // [4096]
  float* hidden  = predOut + B_DIM + 1;       // [4097 ..]

  cast_tile<<<(B_DIM / 128) * NKT, 256, 0, stream>>>(state, inputX, Xc);
  cast_tile<<<(H_DIM / 128) * NKT, 256, 0, stream>>>(W_t, W_x, Wc);

  gemm_splitk<<<256 * S, 256, 0, stream>>>(Xc, Wc, P, NKT / S);
  reduce_bias_tanh<<<2048, 256, 0, stream>>>(P, b_t, b_x, hidden, S);

  pred_err<<<B_DIM, 256, 0, stream>>>(hidden, inputY, truth, W_y, b_y, predOut, bce);
  reduce_err<<<1, 256, 0, stream>>>(bce, errOut);
}